// Round 7
// baseline (217.215 us; speedup 1.0000x reference)
//
#include <hip/hip_runtime.h>
#include <math.h>

// AdaptiveTripletMarginLoss: B=65536 rows, D=256 fp32.
// R6: 16 rows/wave, one group per wave, PACKING butterfly reduction.
//  - 48 nontemporal 1-KiB row-loads per wave (16 KB/stream burst)
//  - packing reduce: merge row-pairs while reducing (48->24->12->6->3
//    values over xor 32/16/8/4, then xor 2/1) = 57 shuffles vs 288 naive
//  - epilogue distributed: all 64 lanes compute loss (4x redundant, x0.25)
//    instead of 16 serial rounds on lane 0

#define D 256
#define TPB 256
#define ROWS_PER_WAVE 16
#define WAVES_PER_BLOCK 4
#define ROWS_PER_BLOCK (ROWS_PER_WAVE * WAVES_PER_BLOCK)   // 64

typedef float nt_float4 __attribute__((ext_vector_type(4)));

// lanes with (lane&mask)==0 end holding reduced `lo` (sum over {l, l^mask});
// lanes with (lane&mask)!=0 end holding reduced `hi`.
__device__ __forceinline__ float pack_merge(float lo, float hi, int mask, int lane) {
    const bool up = (lane & mask) != 0;
    const float send = up ? lo : hi;          // partner keeps this one
    const float recv = __shfl_xor(send, mask, 64);
    return (up ? hi : lo) + recv;
}

__global__ __launch_bounds__(TPB, 4) void triplet_partial(
    const nt_float4* __restrict__ a4, const nt_float4* __restrict__ p4,
    const nt_float4* __restrict__ n4, float* __restrict__ partial, int B)
{
    const int lane = threadIdx.x & 63;
    const int wib  = threadIdx.x >> 6;
    const int g    = blockIdx.x * WAVES_PER_BLOCK + wib;   // one group/wave
    const bool inRange = (g + 1) * ROWS_PER_WAVE <= B;

    float sap[ROWS_PER_WAVE], san[ROWS_PER_WAVE], spn[ROWS_PER_WAVE];

    if (inRange) {
        // row = 64 float4; load j covers row (g*16+j) across the 64 lanes
        const size_t base = (size_t)g * (ROWS_PER_WAVE * 64) + lane;

        nt_float4 av[ROWS_PER_WAVE], pv[ROWS_PER_WAVE], nv[ROWS_PER_WAVE];
        #pragma unroll
        for (int j = 0; j < ROWS_PER_WAVE; ++j)
            av[j] = __builtin_nontemporal_load(a4 + base + (size_t)j * 64);
        #pragma unroll
        for (int j = 0; j < ROWS_PER_WAVE; ++j)
            pv[j] = __builtin_nontemporal_load(p4 + base + (size_t)j * 64);
        #pragma unroll
        for (int j = 0; j < ROWS_PER_WAVE; ++j)
            nv[j] = __builtin_nontemporal_load(n4 + base + (size_t)j * 64);

        #pragma unroll
        for (int j = 0; j < ROWS_PER_WAVE; ++j) {
            float d, s0, s1, s2;
            d = av[j].x - pv[j].x; s0 = d * d;
            d = av[j].y - pv[j].y; s0 = fmaf(d, d, s0);
            d = av[j].z - pv[j].z; s0 = fmaf(d, d, s0);
            d = av[j].w - pv[j].w; s0 = fmaf(d, d, s0);
            d = av[j].x - nv[j].x; s1 = d * d;
            d = av[j].y - nv[j].y; s1 = fmaf(d, d, s1);
            d = av[j].z - nv[j].z; s1 = fmaf(d, d, s1);
            d = av[j].w - nv[j].w; s1 = fmaf(d, d, s1);
            d = pv[j].x - nv[j].x; s2 = d * d;
            d = pv[j].y - nv[j].y; s2 = fmaf(d, d, s2);
            d = pv[j].z - nv[j].z; s2 = fmaf(d, d, s2);
            d = pv[j].w - nv[j].w; s2 = fmaf(d, d, s2);
            sap[j] = s0; san[j] = s1; spn[j] = s2;
        }
    } else {
        #pragma unroll
        for (int j = 0; j < ROWS_PER_WAVE; ++j) {
            sap[j] = 0.0f; san[j] = 0.0f; spn[j] = 0.0f;
        }
    }

    // packing butterfly: halve value count each stage while reducing.
    // After all stages, every lane holds the FULL row-sums of the row
    // encoded by lane bits (5,4,3,2) — 4 lanes per row.
    float a1[8], n1[8], p1[8];
    #pragma unroll
    for (int r = 0; r < 8; ++r) {
        a1[r] = pack_merge(sap[2*r], sap[2*r+1], 32, lane);
        n1[r] = pack_merge(san[2*r], san[2*r+1], 32, lane);
        p1[r] = pack_merge(spn[2*r], spn[2*r+1], 32, lane);
    }
    float a2[4], n2[4], p2[4];
    #pragma unroll
    for (int r = 0; r < 4; ++r) {
        a2[r] = pack_merge(a1[2*r], a1[2*r+1], 16, lane);
        n2[r] = pack_merge(n1[2*r], n1[2*r+1], 16, lane);
        p2[r] = pack_merge(p1[2*r], p1[2*r+1], 16, lane);
    }
    float a3[2], n3[2], p3[2];
    #pragma unroll
    for (int r = 0; r < 2; ++r) {
        a3[r] = pack_merge(a2[2*r], a2[2*r+1], 8, lane);
        n3[r] = pack_merge(n2[2*r], n2[2*r+1], 8, lane);
        p3[r] = pack_merge(p2[2*r], p2[2*r+1], 8, lane);
    }
    float fa = pack_merge(a3[0], a3[1], 4, lane);
    float fn = pack_merge(n3[0], n3[1], 4, lane);
    float fp = pack_merge(p3[0], p3[1], 4, lane);
    // finish the reduction within each 4-lane segment (bits 1,0)
    fa += __shfl_xor(fa, 2, 64); fa += __shfl_xor(fa, 1, 64);
    fn += __shfl_xor(fn, 2, 64); fn += __shfl_xor(fn, 1, 64);
    fp += __shfl_xor(fp, 2, 64); fp += __shfl_xor(fp, 1, 64);

    // epilogue on ALL lanes (each row computed on its 4 lanes -> x0.25)
    float local = 0.0f;
    if (inRange) {
        const float dap = sqrtf(fa);
        const float dan = sqrtf(fn);
        const float dpn = sqrtf(fp);
        // exp(4*dap) ~ exp(90) -> inf -> term 0 (matches ref fp32)
        const float msim = 1.0f + 2.0f / (__expf(4.0f * dap) + 1e-6f);
        // exp(-4*dan+4) underflows vs 1e-6 -> term ~2e6 (dominates loss)
        const float mdis = 1.0f + 2.0f / (__expf(-4.0f * dan + 4.0f) + 1e-6f);
        local = 0.25f * (dap - 0.5f * (dan + dpn) + msim + mdis);
    }

    // wave total (sums all 16 rows of this wave), then block total
    #pragma unroll
    for (int off = 32; off >= 1; off >>= 1)
        local += __shfl_xor(local, off, 64);

    __shared__ float sm[WAVES_PER_BLOCK];
    if (lane == 0) sm[wib] = local;
    __syncthreads();
    if (threadIdx.x == 0) {
        float s = 0.0f;
        #pragma unroll
        for (int i = 0; i < WAVES_PER_BLOCK; ++i) s += sm[i];
        partial[blockIdx.x] = s;
    }
}

__global__ __launch_bounds__(256) void final_reduce(
    const float* __restrict__ partial, float* __restrict__ out,
    int nPartial, float invB)
{
    float s = 0.0f;
    for (int i = threadIdx.x; i < nPartial; i += blockDim.x) s += partial[i];
    #pragma unroll
    for (int off = 32; off > 0; off >>= 1) s += __shfl_xor(s, off, 64);

    __shared__ float sm[4];
    const int lane = threadIdx.x & 63;
    const int w = threadIdx.x >> 6;
    if (lane == 0) sm[w] = s;
    __syncthreads();
    if (threadIdx.x == 0) out[0] = (sm[0] + sm[1] + sm[2] + sm[3]) * invB;
}

extern "C" void kernel_launch(void* const* d_in, const int* in_sizes, int n_in,
                              void* d_out, int out_size, void* d_ws, size_t ws_size,
                              hipStream_t stream) {
    const nt_float4* a = (const nt_float4*)d_in[0];
    const nt_float4* p = (const nt_float4*)d_in[1];
    const nt_float4* n = (const nt_float4*)d_in[2];
    float* out = (float*)d_out;
    float* partial = (float*)d_ws;   // nBlocks floats scratch

    const int B = in_sizes[0] / D;   // 65536
    const int nBlocks = (B + ROWS_PER_BLOCK - 1) / ROWS_PER_BLOCK;  // 1024

    triplet_partial<<<nBlocks, TPB, 0, stream>>>(a, p, n, partial, B);
    final_reduce<<<1, 256, 0, stream>>>(partial, out, nBlocks, 1.0f / (float)B);
}

// Round 8
// 175.317 us; speedup vs baseline: 1.2390x; 1.2390x over previous
//
#include <hip/hip_runtime.h>
#include <math.h>

// AdaptiveTripletMarginLoss: B=65536 rows, D=256 fp32.
// R7: R5's memory structure (8 rows/wave -> no spill) + cheap reduction.
//  - 24 nontemporal 1-KiB row-loads per wave-iter (VGPR ~60, verified no spill)
//  - 1024 blocks, grid-stride exactly 2 iters/wave
//  - packing butterfly: 24 sums -> 12 -> 6 -> 3 (xor 32/16/8), then 9
//    in-segment butterflies = 39 shuffles vs 144 naive
//  - distributed epilogue: all 64 lanes (8-way redundant, x1/8) instead of
//    8 serial transcendental rounds on lane 0
//  - loss accumulated per-lane; ONE wave reduce after the loop

#define D 256
#define TPB 256
#define ROWS_PER_WAVE 8
#define WAVES_PER_BLOCK 4
#define NBLOCKS 1024

typedef float nt_float4 __attribute__((ext_vector_type(4)));

// lanes with (lane&mask)==0 end holding sum-over-pair of `lo`;
// lanes with (lane&mask)!=0 end holding sum-over-pair of `hi`.
__device__ __forceinline__ float pack_merge(float lo, float hi, int mask, int lane) {
    const bool up = (lane & mask) != 0;
    const float send = up ? lo : hi;          // partner keeps this one
    const float recv = __shfl_xor(send, mask, 64);
    return (up ? hi : lo) + recv;
}

__global__ __launch_bounds__(TPB, 4) void triplet_partial(
    const nt_float4* __restrict__ a4, const nt_float4* __restrict__ p4,
    const nt_float4* __restrict__ n4, float* __restrict__ partial, int B)
{
    const int lane = threadIdx.x & 63;
    const int wib  = threadIdx.x >> 6;
    const int waveId = blockIdx.x * WAVES_PER_BLOCK + wib;
    const int nWaves = NBLOCKS * WAVES_PER_BLOCK;          // 4096
    const int nGroups = B / ROWS_PER_WAVE;                 // 8192

    // lane's row-slot within each 8-row group (set by packing order):
    // bit5 -> row bit0, bit4 -> row bit1, bit3 -> row bit2
    float local = 0.0f;

    for (int g = waveId; g < nGroups; g += nWaves) {
        const size_t base = (size_t)g * (ROWS_PER_WAVE * 64) + lane;

        nt_float4 av[ROWS_PER_WAVE], pv[ROWS_PER_WAVE], nv[ROWS_PER_WAVE];
        #pragma unroll
        for (int j = 0; j < ROWS_PER_WAVE; ++j)
            av[j] = __builtin_nontemporal_load(a4 + base + (size_t)j * 64);
        #pragma unroll
        for (int j = 0; j < ROWS_PER_WAVE; ++j)
            pv[j] = __builtin_nontemporal_load(p4 + base + (size_t)j * 64);
        #pragma unroll
        for (int j = 0; j < ROWS_PER_WAVE; ++j)
            nv[j] = __builtin_nontemporal_load(n4 + base + (size_t)j * 64);

        float sap[ROWS_PER_WAVE], san[ROWS_PER_WAVE], spn[ROWS_PER_WAVE];
        #pragma unroll
        for (int j = 0; j < ROWS_PER_WAVE; ++j) {
            float d, s0, s1, s2;
            d = av[j].x - pv[j].x; s0 = d * d;
            d = av[j].y - pv[j].y; s0 = fmaf(d, d, s0);
            d = av[j].z - pv[j].z; s0 = fmaf(d, d, s0);
            d = av[j].w - pv[j].w; s0 = fmaf(d, d, s0);
            d = av[j].x - nv[j].x; s1 = d * d;
            d = av[j].y - nv[j].y; s1 = fmaf(d, d, s1);
            d = av[j].z - nv[j].z; s1 = fmaf(d, d, s1);
            d = av[j].w - nv[j].w; s1 = fmaf(d, d, s1);
            d = pv[j].x - nv[j].x; s2 = d * d;
            d = pv[j].y - nv[j].y; s2 = fmaf(d, d, s2);
            d = pv[j].z - nv[j].z; s2 = fmaf(d, d, s2);
            d = pv[j].w - nv[j].w; s2 = fmaf(d, d, s2);
            sap[j] = s0; san[j] = s1; spn[j] = s2;
        }

        // packing butterfly: 24 -> 12 -> 6 -> 3 values
        float a1[4], n1[4], p1[4];
        #pragma unroll
        for (int r = 0; r < 4; ++r) {           // xor 32: row bit0 <- lane bit5
            a1[r] = pack_merge(sap[2*r], sap[2*r+1], 32, lane);
            n1[r] = pack_merge(san[2*r], san[2*r+1], 32, lane);
            p1[r] = pack_merge(spn[2*r], spn[2*r+1], 32, lane);
        }
        float a2[2], n2[2], p2[2];
        #pragma unroll
        for (int r = 0; r < 2; ++r) {           // xor 16: row bit1 <- lane bit4
            a2[r] = pack_merge(a1[2*r], a1[2*r+1], 16, lane);
            n2[r] = pack_merge(n1[2*r], n1[2*r+1], 16, lane);
            p2[r] = pack_merge(p1[2*r], p1[2*r+1], 16, lane);
        }
        float fa = pack_merge(a2[0], a2[1], 8, lane);   // row bit2 <- lane bit3
        float fn = pack_merge(n2[0], n2[1], 8, lane);
        float fp = pack_merge(p2[0], p2[1], 8, lane);

        // finish within each 8-lane segment (bits 2,1,0)
        fa += __shfl_xor(fa, 4, 64); fa += __shfl_xor(fa, 2, 64); fa += __shfl_xor(fa, 1, 64);
        fn += __shfl_xor(fn, 4, 64); fn += __shfl_xor(fn, 2, 64); fn += __shfl_xor(fn, 1, 64);
        fp += __shfl_xor(fp, 4, 64); fp += __shfl_xor(fp, 2, 64); fp += __shfl_xor(fp, 1, 64);

        // distributed epilogue: every lane holds full sums of ONE row
        // (8 lanes per row -> scale by 1/8)
        const float dap = sqrtf(fa);
        const float dan = sqrtf(fn);
        const float dpn = sqrtf(fp);
        // exp(4*dap) ~ exp(90) -> inf -> term 0 (matches ref fp32)
        const float msim = 1.0f + 2.0f / (__expf(4.0f * dap) + 1e-6f);
        // exp(-4*dan+4) underflows vs 1e-6 -> term ~2e6 (dominates loss)
        const float mdis = 1.0f + 2.0f / (__expf(-4.0f * dan + 4.0f) + 1e-6f);
        local += 0.125f * (dap - 0.5f * (dan + dpn) + msim + mdis);
    }

    // one wave reduce at the end: sums all rows this wave processed
    #pragma unroll
    for (int off = 32; off >= 1; off >>= 1)
        local += __shfl_xor(local, off, 64);

    __shared__ float sm[WAVES_PER_BLOCK];
    if (lane == 0) sm[wib] = local;
    __syncthreads();
    if (threadIdx.x == 0) {
        float s = 0.0f;
        #pragma unroll
        for (int i = 0; i < WAVES_PER_BLOCK; ++i) s += sm[i];
        partial[blockIdx.x] = s;
    }
}

__global__ __launch_bounds__(256) void final_reduce(
    const float* __restrict__ partial, float* __restrict__ out,
    int nPartial, float invB)
{
    float s = 0.0f;
    for (int i = threadIdx.x; i < nPartial; i += blockDim.x) s += partial[i];
    #pragma unroll
    for (int off = 32; off > 0; off >>= 1) s += __shfl_xor(s, off, 64);

    __shared__ float sm[4];
    const int lane = threadIdx.x & 63;
    const int w = threadIdx.x >> 6;
    if (lane == 0) sm[w] = s;
    __syncthreads();
    if (threadIdx.x == 0) out[0] = (sm[0] + sm[1] + sm[2] + sm[3]) * invB;
}

extern "C" void kernel_launch(void* const* d_in, const int* in_sizes, int n_in,
                              void* d_out, int out_size, void* d_ws, size_t ws_size,
                              hipStream_t stream) {
    const nt_float4* a = (const nt_float4*)d_in[0];
    const nt_float4* p = (const nt_float4*)d_in[1];
    const nt_float4* n = (const nt_float4*)d_in[2];
    float* out = (float*)d_out;
    float* partial = (float*)d_ws;   // NBLOCKS floats (4 KiB) scratch

    const int B = in_sizes[0] / D;   // 65536

    triplet_partial<<<NBLOCKS, TPB, 0, stream>>>(a, p, n, partial, B);
    final_reduce<<<1, 256, 0, stream>>>(partial, out, NBLOCKS, 1.0f / (float)B);
}